// Round 1
// baseline (207.059 us; speedup 1.0000x reference)
//
#include <hip/hip_runtime.h>
#include <hip/hip_bf16.h>

// Joiner: out[b,t,u,v] = tanh(enc[b,t,:] + pred[b,u,:]) . W[v,:] + bias[v]
// B=8 T=512 U=128 D=256 V=128, all fp32 in/out. bf16 MFMA for the matmul.

constexpr int Bn = 8, Tn = 512, Un = 128, Dn = 256, Vn = 128;

typedef __attribute__((ext_vector_type(8))) short bf16x8;   // 8 bf16 = 4 VGPRs
typedef __attribute__((ext_vector_type(4))) float f32x4;

// fp32 -> bf16 round-to-nearest-even (finite inputs only)
static __device__ __forceinline__ unsigned short f2bf(float f) {
    unsigned int u = __float_as_uint(f);
    unsigned int r = (u + 0x7fffu + ((u >> 16) & 1u)) >> 16;
    return (unsigned short)r;
}

// tanh(x) = (e-1)/(e+1), e = exp(2x); clamp so e stays finite; v_exp + v_rcp
static __device__ __forceinline__ float fast_tanh(float x) {
    x = fminf(8.f, fmaxf(-8.f, x));
    float e = __expf(2.f * x);
    return (e - 1.f) * __builtin_amdgcn_rcpf(e + 1.f);
}

__global__ __launch_bounds__(256) void cvtW_kernel(const float* __restrict__ W,
                                                   unsigned short* __restrict__ Wb) {
    int i = blockIdx.x * 256 + threadIdx.x;          // 32 blocks * 256 * 4 elems = 32768
    float4 v = ((const float4*)W)[i];
    union { bf16x8 dummy; } u_;
    (void)u_;
    unsigned short r0 = f2bf(v.x), r1 = f2bf(v.y), r2 = f2bf(v.z), r3 = f2bf(v.w);
    unsigned long long packed = (unsigned long long)r0 | ((unsigned long long)r1 << 16) |
                                ((unsigned long long)r2 << 32) | ((unsigned long long)r3 << 48);
    ((unsigned long long*)Wb)[i] = packed;
}

__global__ __launch_bounds__(256) void joiner_kernel(
    const float* __restrict__ enc,      // [B,T,D]
    const float* __restrict__ pred,     // [B,U,D]
    const unsigned short* __restrict__ Wb, // [V,D] bf16 bits
    const float* __restrict__ bias,     // [V]
    float* __restrict__ out)            // [B,T,U,V]
{
    const int bid = blockIdx.x;         // = b*Tn + t
    const int b   = bid >> 9;           // /512
    const int tid = threadIdx.x;
    const int w   = tid >> 6;           // wave 0..3 -> u rows [w*32, w*32+32)
    const int l   = tid & 63;
    const int l16 = l & 15;
    const int lq  = l >> 4;             // 0..3

    const float* encRow = enc + (size_t)bid * Dn;
    const float* predB  = pred + (size_t)b * Un * Dn;

    f32x4 acc[2][8];
#pragma unroll
    for (int m = 0; m < 2; ++m)
#pragma unroll
        for (int n = 0; n < 8; ++n)
            acc[m][n] = (f32x4){0.f, 0.f, 0.f, 0.f};

    const int u_base = w * 32;

    for (int kk = 0; kk < 8; ++kk) {
        const int d0 = kk * 32 + lq * 8;

        // enc slice (same for lanes with equal lq -> broadcast from L1)
        float4 e0 = *(const float4*)(encRow + d0);
        float4 e1 = *(const float4*)(encRow + d0 + 4);
        float ev[8] = {e0.x, e0.y, e0.z, e0.w, e1.x, e1.y, e1.z, e1.w};

        // A fragments: tanh(enc + pred) -> bf16, computed in registers
        bf16x8 afr[2];
#pragma unroll
        for (int m = 0; m < 2; ++m) {
            const float* pr = predB + (size_t)(u_base + m * 16 + l16) * Dn + d0;
            float4 p0 = *(const float4*)(pr);
            float4 p1 = *(const float4*)(pr + 4);
            float pv[8] = {p0.x, p0.y, p0.z, p0.w, p1.x, p1.y, p1.z, p1.w};
            bf16x8 af;
#pragma unroll
            for (int j = 0; j < 8; ++j) {
                float t = fast_tanh(ev[j] + pv[j]);
                af[j] = (short)f2bf(t);
            }
            afr[m] = af;
        }

        // B fragments: W rows, contiguous 8 bf16 along K
        bf16x8 bfr[8];
#pragma unroll
        for (int n = 0; n < 8; ++n) {
            const unsigned short* wp = Wb + (size_t)(n * 16 + l16) * Dn + d0;
            bfr[n] = *(const bf16x8*)wp;
        }

#pragma unroll
        for (int m = 0; m < 2; ++m)
#pragma unroll
            for (int n = 0; n < 8; ++n)
                acc[m][n] = __builtin_amdgcn_mfma_f32_16x16x32_bf16(afr[m], bfr[n], acc[m][n], 0, 0, 0);
    }

    // Epilogue: C/D layout col = lane&15 (v), row = lq*4 + r (u)
    float* outB = out + (size_t)bid * (Un * Vn);
#pragma unroll
    for (int n = 0; n < 8; ++n) {
        const int v = n * 16 + l16;
        const float bv = bias[v];
#pragma unroll
        for (int m = 0; m < 2; ++m) {
            const int u0 = u_base + m * 16 + lq * 4;
#pragma unroll
            for (int r = 0; r < 4; ++r) {
                outB[(size_t)(u0 + r) * Vn + v] = acc[m][n][r] + bv;
            }
        }
    }
}

extern "C" void kernel_launch(void* const* d_in, const int* in_sizes, int n_in,
                              void* d_out, int out_size, void* d_ws, size_t ws_size,
                              hipStream_t stream) {
    const float* enc  = (const float*)d_in[0];
    const float* pred = (const float*)d_in[1];
    const float* W    = (const float*)d_in[2];
    const float* bias = (const float*)d_in[3];
    float* out = (float*)d_out;
    unsigned short* Wb = (unsigned short*)d_ws;   // 32768 bf16 = 64 KB

    cvtW_kernel<<<32, 256, 0, stream>>>(W, Wb);                 // re-run every call
    joiner_kernel<<<Bn * Tn, 256, 0, stream>>>(enc, pred, Wb, bias, out);
}